// Round 3
// baseline (151.620 us; speedup 1.0000x reference)
//
#include <hip/hip_runtime.h>

// Predictive-coding graph message passing, MI355X — round 13.
// R12 post-mortem: k_bucket + 2x k_pass ~= 78us. k_pass was latency-bound:
// value gather issued only 2 iters before use (~300-450cy L2 latency vs
// ~30cy of cover), stalls serial per wave, 1 block/CU -> ~15-20us/pass.
// k_bucket ran 2 sequential dirs x 16-barrier Hillis-Steele on 1024 thr
// (~48 barriers) and read the edge list twice per dir, on only 128 CUs.
// R13: (a) 6-deep value pipeline in k_pass (stall ~= lat/5);
//      (b) k_bucket stages (src,dst,w) in LDS once, single-wave shfl scan
//          (11 barriers total), 256 bucketing blocks so all CUs work.

static constexpr int kB = 32, kLogB = 5;
static constexpr int kBkt = 256;         // coarse buckets (16 nodes each)
static constexpr int kNPB = 16;          // nodes per bucket
static constexpr int kCap = 2560;        // records/bucket: mean 2048, +11sigma
static constexpr int kChunk = 2048;      // edges per bucketing block

// ---- K1: fused transpose/tanh + dual-direction LDS bucket sort. ---------
__global__ void __launch_bounds__(1024) k_bucket(
    const float* __restrict__ x, const float* __restrict__ w,
    const int* __restrict__ esrc, const int* __restrict__ edst,
    float* __restrict__ x_t, float* __restrict__ fx_t,
    unsigned* __restrict__ gcntA, unsigned* __restrict__ gcntB,
    uint2* __restrict__ bucketA, uint2* __restrict__ bucketB,
    int N, int E, int nBB) {
  __shared__ int sS[kChunk], sD[kChunk];         // 16 KB staged edge ids
  __shared__ float sW[kChunk];                   // 8 KB staged weights
  __shared__ unsigned cntL[kBkt], baseL[kBkt], gbase[kBkt], cnt2[kBkt];
  __shared__ uint2 cmp[kChunk];                  // 16 KB sorted records
  __shared__ unsigned char bkt[kChunk];          // bucket id per slot
  __shared__ float tile[32][65];
  int tid = threadIdx.x, blk = blockIdx.x;

  if (blk < nBB) {
    int e0 = blk * kChunk;
    int len = min(kChunk, E - e0);
#pragma unroll
    for (int k = 0; k < kChunk / 1024; k++) {    // stage edges ONCE
      int i = k * 1024 + tid;
      if (i < len) { sS[i] = esrc[e0 + i]; sD[i] = edst[e0 + i]; sW[i] = w[e0 + i]; }
    }
    __syncthreads();
    for (int dir = 0; dir < 2; ++dir) {
      const int* key = dir ? sS : sD;            // A: by dst, B: by src
      const int* oth = dir ? sD : sS;
      unsigned* gcnt = dir ? gcntB : gcntA;
      uint2* out = dir ? bucketB : bucketA;

      if (tid < kBkt) { cntL[tid] = 0u; cnt2[tid] = 0u; }
      __syncthreads();
#pragma unroll
      for (int k = 0; k < kChunk / 1024; k++) {  // histogram (from LDS)
        int i = k * 1024 + tid;
        if (i < len) atomicAdd(&cntL[((unsigned)key[i]) >> 4], 1u);
      }
      __syncthreads();
      if (tid < 64) {                            // single-wave scan, 4 bins/lane
        int q = tid << 2;
        unsigned c0 = cntL[q], c1 = cntL[q + 1], c2 = cntL[q + 2], c3 = cntL[q + 3];
        unsigned s = c0 + c1 + c2 + c3;
        unsigned run = s;
#pragma unroll
        for (int o = 1; o < 64; o <<= 1) {
          unsigned v = __shfl_up(run, o, 64);
          if (tid >= o) run += v;
        }
        unsigned base = run - s;                 // exclusive base of lane group
        baseL[q]     = base;
        baseL[q + 1] = base + c0;
        baseL[q + 2] = base + c0 + c1;
        baseL[q + 3] = base + c0 + c1 + c2;
        gbase[q]     = c0 ? atomicAdd(&gcnt[q],     c0) : 0u;   // 1 atomic/run
        gbase[q + 1] = c1 ? atomicAdd(&gcnt[q + 1], c1) : 0u;
        gbase[q + 2] = c2 ? atomicAdd(&gcnt[q + 2], c2) : 0u;
        gbase[q + 3] = c3 ? atomicAdd(&gcnt[q + 3], c3) : 0u;
      }
      __syncthreads();
#pragma unroll
      for (int k = 0; k < kChunk / 1024; k++) {  // LDS scatter (sort)
        int i = k * 1024 + tid;
        if (i < len) {
          unsigned ky = (unsigned)key[i];
          unsigned bb = ky >> 4;
          unsigned slot = baseL[bb] + atomicAdd(&cnt2[bb], 1u);
          cmp[slot] = make_uint2((((unsigned)oth[i]) << 4) | (ky & 15u),
                                 __float_as_uint(sW[i]));
          bkt[slot] = (unsigned char)bb;
        }
      }
      __syncthreads();
#pragma unroll
      for (int k = 0; k < kChunk / 1024; k++) {  // coalesced run copy-out
        int s = k * 1024 + tid;
        if (s < len) {
          unsigned bb = bkt[s];
          unsigned pos = gbase[bb] + ((unsigned)s - baseL[bb]);
          if (pos < kCap) out[(size_t)bb * kCap + pos] = cmp[s];
        }
      }
      __syncthreads();                           // cntL/cmp reused next dir
    }
  } else if (blk - nBB < (N >> 6)) {
    // Transpose/tanh: disjoint LDS array, disjoint blocks.
    int n0 = (blk - nBB) * 64;
    for (int k = tid; k < 32 * 64; k += 1024) {  // coalesced 256B rows
      int b = k >> 6, n = k & 63;
      tile[b][n] = x[b * N + n0 + n];
    }
    __syncthreads();
    for (int k = tid; k < 64 * 32; k += 1024) {  // coalesced t-layout
      int n = k >> 5, b = k & 31;
      float xv = tile[b][n];
      int j = (n0 + n) * kB + b;
      x_t[j] = xv;
      fx_t[j] = tanhf(xv);
    }
  }
}

// ---- K2/K3: per-bucket fine sort (16 bins) + per-node VGPR accumulation.
// 1024 thr = 32 half-waves = 16 nodes x 2 parts. Value gather pipelined
// 6-deep: the value consumed at iter i was issued at iter i-5, so the
// ~300-450cy L2 latency is covered by ~5 iteration bodies (R12's depth-2
// stalled ~400cy/iter — the measured 15-20us/pass).
__global__ void __launch_bounds__(1024) k_pass(
    const uint2* __restrict__ bucket, const unsigned* __restrict__ gcnt,
    const float* __restrict__ vals, const float* __restrict__ x_t,
    const float* __restrict__ fx_t, float* __restrict__ eps_t,
    float* __restrict__ out, int N, int mode) {
  __shared__ uint2 stg[kCap];            // 20 KB staged records
  __shared__ uint2 srt[kCap];            // 20 KB node-sorted records
  __shared__ unsigned h[kNPB], hb[kNPB], h2[kNPB];
  __shared__ float red[1024];
  int tid = threadIdx.x, t = blockIdx.x;
  int nrec = min((int)gcnt[t], kCap);

  if (tid < kNPB) { h[tid] = 0u; h2[tid] = 0u; }
  __syncthreads();
  for (int i = tid; i < nrec; i += 1024) {       // stage + 16-bin hist
    uint2 r = bucket[(size_t)t * kCap + i];
    stg[i] = r;
    atomicAdd(&h[r.x & 15u], 1u);
  }
  __syncthreads();
  if (tid == 0) {                                // serial 16-scan
    unsigned run = 0;
#pragma unroll
    for (int l = 0; l < kNPB; l++) { hb[l] = run; run += h[l]; }
  }
  __syncthreads();
  for (int i = tid; i < nrec; i += 1024) {       // LDS fine sort
    uint2 r = stg[i];
    unsigned l = r.x & 15u;
    srt[hb[l] + atomicAdd(&h2[l], 1u)] = r;
  }
  __syncthreads();

  int b = tid & 31, hw = tid >> 5;       // batch lane, half-wave slot
  int l = hw >> 1, part = hw & 1;        // node-in-bucket, edge part
  int beg = (int)hb[l], end = beg + (int)h[l];
  float acc = 0.0f;
  int i = beg + part;
  uint2 z = make_uint2(0u, 0u);
  // 6-deep record/value pipeline (records LDS-broadcast, values L2 gather).
  uint2 r0 = (i          < end) ? srt[i]          : z;
  uint2 r1 = (i + 2      < end) ? srt[i + 2]      : z;
  uint2 r2 = (i + 4      < end) ? srt[i + 4]      : z;
  uint2 r3 = (i + 6      < end) ? srt[i + 6]      : z;
  uint2 r4 = (i + 8      < end) ? srt[i + 8]      : z;
  uint2 r5 = (i + 10     < end) ? srt[i + 10]     : z;
  float v0 = (i          < end) ? vals[((r0.x >> 4) << kLogB) + b] : 0.0f;
  float v1 = (i + 2      < end) ? vals[((r1.x >> 4) << kLogB) + b] : 0.0f;
  float v2 = (i + 4      < end) ? vals[((r2.x >> 4) << kLogB) + b] : 0.0f;
  float v3 = (i + 6      < end) ? vals[((r3.x >> 4) << kLogB) + b] : 0.0f;
  float v4 = (i + 8      < end) ? vals[((r4.x >> 4) << kLogB) + b] : 0.0f;
  while (i < end) {
    uint2 r6 = (i + 12 < end) ? srt[i + 12] : z;
    float v5 = (i + 10 < end) ? vals[((r5.x >> 4) << kLogB) + b] : 0.0f;
    acc = fmaf(__uint_as_float(r0.y), v0, acc);
    r0 = r1; r1 = r2; r2 = r3; r3 = r4; r4 = r5; r5 = r6;
    v0 = v1; v1 = v2; v2 = v3; v3 = v4; v4 = v5;
    i += 2;
  }
  red[tid] = acc;
  __syncthreads();

  if (part == 0) {                       // combine 2 parts, write outputs
    float s = red[tid] + red[tid + 32];
    int n = t * kNPB + l;
    int j = (n << kLogB) + b;
    if (mode == 0) {
      out[b * N + n] = s;                // mu (batch-major; 64B line/bucket/b)
      eps_t[j] = x_t[j] - s;
    } else {
      float fx = fx_t[j];
      out[b * N + n] = fmaf(1.0f - fx * fx, s, -eps_t[j]);   // dx
    }
  }
}

extern "C" void kernel_launch(void* const* d_in, const int* in_sizes, int n_in,
                              void* d_out, int out_size, void* d_ws, size_t ws_size,
                              hipStream_t stream) {
  const float* x    = (const float*)d_in[0];
  const float* w    = (const float*)d_in[1];
  const int*   esrc = (const int*)d_in[2];
  const int*   edst = (const int*)d_in[3];

  int BN = in_sizes[0];                  // 131072
  int E  = in_sizes[1];                  // 524288
  int N  = BN / kB;                      // 4096
  int nBB = (E + kChunk - 1) / kChunk;   // 256

  float* ws    = (float*)d_ws;
  float* x_t   = ws;                     // [BN]
  float* fx_t  = ws + (size_t)BN;        // [BN]
  float* eps_t = ws + 2 * (size_t)BN;    // [BN]
  unsigned* gcntA = (unsigned*)(ws + 3 * (size_t)BN);   // [256]
  unsigned* gcntB = gcntA + kBkt;                       // [256]
  uint2* bucketA = (uint2*)(gcntB + kBkt);              // [256*2560] 5.2 MB
  uint2* bucketB = bucketA + (size_t)kBkt * kCap;       // [256*2560] 5.2 MB

  float* out_mu = (float*)d_out;
  float* out_dx = (float*)d_out + BN;

  // Zero bucket counters (workspace is poisoned each iteration).
  hipMemsetAsync(gcntA, 0, (size_t)2 * kBkt * sizeof(unsigned), stream);

  k_bucket<<<nBB + (N >> 6), 1024, 0, stream>>>(x, w, esrc, edst, x_t, fx_t,
                                                gcntA, gcntB, bucketA, bucketB,
                                                N, E, nBB);
  // Pass 1: mu[n] = sum_{e: dst=n} w_e * fx[src_e]; eps = x - mu.
  k_pass<<<kBkt, 1024, 0, stream>>>(bucketA, gcntA, fx_t, x_t, fx_t,
                                    eps_t, out_mu, N, 0);
  // Pass 2: dx[n] = -eps[n] + f'(x_n) * sum_{e: src=n} w_e * eps[dst_e].
  k_pass<<<kBkt, 1024, 0, stream>>>(bucketB, gcntB, eps_t, x_t, fx_t,
                                    eps_t, out_dx, N, 1);
}

// Round 4
// 107.452 us; speedup vs baseline: 1.4111x; 1.4111x over previous
//
#include <hip/hip_runtime.h>

// Predictive-coding graph message passing, MI355X — round 14.
// R13 post-mortem: (a) k_bucket 43.5us with VALU 1.9%/HBM 4.7% — pure stall:
// 131K device-scope atomicAdds onto 512 words (run reservation) executed by
// one wave per block between barriers. (b) k_pass never sped up: the value
// pipeline used `cond ? vals[..] : 0` — the cndmask consumes the load in the
// SAME iteration it issues => s_waitcnt vmcnt(0) per iteration at any depth.
// R14: zero global atomics. Deterministic two-level counting sort:
//   K1 k_hist: per-chunk 256-bucket histograms (non-atomic row writes)
//              + fused transpose/tanh.
//   K2 k_scan: scan the [chunk][bucket] count matrix (4-way split, 8-unrolled
//              coalesced loads) -> absolute per-(chunk,bucket) bases + dense
//              segment bounds. Exact counts: no padding, no dropped edges.
//   K3 k_scatter: LDS sort per chunk + coalesced run copy-out (mean 64B runs).
//   K4/K5 k_pass: per-bucket fine sort (per-wave privatized 16-bin counters),
//              then SELECT-FREE pipelined accumulation: unconditional clamped
//              loads (srt[min(p,last)], node &4095), predicate applied to the
//              WEIGHT only (integer test) -> 8 loads stay in flight.

static constexpr int kB = 32, kLogB = 5;
static constexpr int kBkt = 256;        // coarse buckets (16 nodes each)
static constexpr int kNPB = 16;         // nodes per bucket
static constexpr int kChunk = 2048;     // edges per chunk block
static constexpr int kTile = 2560;      // k_pass LDS tile (mean 2048, +11sigma)

// ---- K1: per-chunk dual histograms + fused transpose/tanh. --------------
__global__ void __launch_bounds__(1024) k_hist(
    const int* __restrict__ esrc, const int* __restrict__ edst,
    const float* __restrict__ x, float* __restrict__ x_t,
    float* __restrict__ fx_t, unsigned* __restrict__ cntA,
    unsigned* __restrict__ cntB, int N, int E, int nBB) {
  __shared__ unsigned hA[kBkt], hB[kBkt];
  __shared__ float tile[32][65];
  int tid = threadIdx.x, blk = blockIdx.x;
  if (blk < nBB) {
    if (tid < kBkt) { hA[tid] = 0u; hB[tid] = 0u; }
    __syncthreads();
    int e0 = blk * kChunk, len = min(kChunk, E - e0);
    for (int i = tid; i < len; i += 1024) {
      atomicAdd(&hA[((unsigned)edst[e0 + i]) >> 4], 1u);  // ~8/bin: cheap
      atomicAdd(&hB[((unsigned)esrc[e0 + i]) >> 4], 1u);
    }
    __syncthreads();
    if (tid < kBkt) {                    // non-atomic coalesced row write
      cntA[(size_t)blk * kBkt + tid] = hA[tid];
      cntB[(size_t)blk * kBkt + tid] = hB[tid];
    }
  } else if (blk - nBB < (N >> 6)) {
    int n0 = (blk - nBB) * 64;
    for (int k = tid; k < 32 * 64; k += 1024) {  // coalesced 256B rows
      int b = k >> 6, n = k & 63;
      tile[b][n] = x[b * N + n0 + n];
    }
    __syncthreads();
    for (int k = tid; k < 64 * 32; k += 1024) {  // coalesced t-layout
      int n = k >> 5, b = k & 31;
      float xv = tile[b][n];
      int j = (n0 + n) * kB + b;
      x_t[j] = xv;
      fx_t[j] = tanhf(xv);
    }
  }
}

// ---- K2: scan [chunk][bucket] counts -> absolute bases + segment bounds.
// 2 blocks (one per direction) x 1024 thr; thread (q,t) owns quarter q of
// the chunk range for bucket t. 8-unrolled coalesced loads keep 8 in flight.
__global__ void __launch_bounds__(1024) k_scan(
    const unsigned* __restrict__ cntA, const unsigned* __restrict__ cntB,
    unsigned* __restrict__ baseA, unsigned* __restrict__ baseB,
    unsigned* __restrict__ segA, unsigned* __restrict__ segB, int nBB) {
  __shared__ unsigned qoff[4][kBkt];
  __shared__ unsigned tot[kBkt];
  __shared__ unsigned bb[kBkt];
  const unsigned* cnt = blockIdx.x ? cntB : cntA;
  unsigned* base = blockIdx.x ? baseB : baseA;
  unsigned* seg  = blockIdx.x ? segB  : segA;
  int tid = threadIdx.x;
  int t = tid & (kBkt - 1), q = tid >> 8;
  int qlen = (nBB + 3) >> 2;
  int b0 = q * qlen;
  unsigned run = 0;
  for (int j = 0; j < qlen; j += 8) {
    unsigned c[8];
#pragma unroll
    for (int u = 0; u < 8; ++u) {
      int bi = b0 + j + u;
      c[u] = (bi < nBB) ? cnt[(size_t)bi * kBkt + t] : 0u;
    }
#pragma unroll
    for (int u = 0; u < 8; ++u) run += c[u];
  }
  qoff[q][t] = run;
  __syncthreads();
  unsigned myTot = 0;
  if (tid < kBkt) {                      // quarter offsets + bucket totals
    unsigned p0 = qoff[0][tid], p1 = qoff[1][tid];
    unsigned p2 = qoff[2][tid], p3 = qoff[3][tid];
    qoff[0][tid] = 0u; qoff[1][tid] = p0;
    qoff[2][tid] = p0 + p1; qoff[3][tid] = p0 + p1 + p2;
    myTot = p0 + p1 + p2 + p3;
    tot[tid] = myTot;
  }
  __syncthreads();
  for (int o = 1; o < kBkt; o <<= 1) {   // Hillis-Steele over 256 totals
    unsigned v = 0;
    if (tid < kBkt && tid >= o) v = tot[tid - o];
    __syncthreads();
    if (tid < kBkt && tid >= o) tot[tid] += v;
    __syncthreads();
  }
  if (tid < kBkt) {
    unsigned excl = tot[tid] - myTot;
    bb[tid] = excl;
    seg[tid] = excl;                     // dense segment starts
    if (tid == kBkt - 1) seg[kBkt] = excl + myTot;
  }
  __syncthreads();
  run = bb[t] + qoff[q][t];              // replay: absolute bases
  for (int j = 0; j < qlen; j += 8) {
    unsigned c[8];
#pragma unroll
    for (int u = 0; u < 8; ++u) {
      int bi = b0 + j + u;
      c[u] = (bi < nBB) ? cnt[(size_t)bi * kBkt + t] : 0u;
    }
#pragma unroll
    for (int u = 0; u < 8; ++u) {
      int bi = b0 + j + u;
      if (bi < nBB) base[(size_t)bi * kBkt + t] = run;
      run += c[u];
    }
  }
}

// ---- K3: deterministic scatter into dense bucket segments. --------------
__global__ void __launch_bounds__(1024) k_scatter(
    const int* __restrict__ esrc, const int* __restrict__ edst,
    const float* __restrict__ wgt,
    const unsigned* __restrict__ cntA, const unsigned* __restrict__ cntB,
    const unsigned* __restrict__ baseA, const unsigned* __restrict__ baseB,
    uint2* __restrict__ recA, uint2* __restrict__ recB, int E, int nBB) {
  __shared__ unsigned myBase[kBkt], cntL[kBkt], baseL[kBkt], cnt2[kBkt];
  __shared__ uint2 cmp[kChunk];          // 16 KB chunk-sorted records
  __shared__ unsigned char bktid[kChunk];
  int tid = threadIdx.x, blk = blockIdx.x;
  int e0 = blk * kChunk, len = min(kChunk, E - e0);
  for (int dir = 0; dir < 2; ++dir) {
    const int* key = dir ? esrc : edst;  // A: by dst, B: by src
    const int* oth = dir ? edst : esrc;
    const unsigned* cnt = dir ? cntB : cntA;
    const unsigned* base = dir ? baseB : baseA;
    uint2* out = dir ? recB : recA;
    if (tid < kBkt) {
      myBase[tid] = base[(size_t)blk * kBkt + tid];
      cntL[tid] = cnt[(size_t)blk * kBkt + tid];
      cnt2[tid] = 0u;
    }
    __syncthreads();
    if (tid < 64) {                      // single-wave excl scan, 4 bins/lane
      int qq = tid << 2;
      unsigned c0 = cntL[qq], c1 = cntL[qq + 1];
      unsigned c2 = cntL[qq + 2], c3 = cntL[qq + 3];
      unsigned s = c0 + c1 + c2 + c3, run = s;
#pragma unroll
      for (int o = 1; o < 64; o <<= 1) {
        unsigned v = __shfl_up(run, o, 64);
        if (tid >= o) run += v;
      }
      unsigned bse = run - s;
      baseL[qq] = bse; baseL[qq + 1] = bse + c0;
      baseL[qq + 2] = bse + c0 + c1; baseL[qq + 3] = bse + c0 + c1 + c2;
    }
    __syncthreads();
    for (int i = tid; i < len; i += 1024) {        // LDS sort
      unsigned ky = (unsigned)key[e0 + i], ot = (unsigned)oth[e0 + i];
      unsigned bbk = ky >> 4;
      unsigned slot = baseL[bbk] + atomicAdd(&cnt2[bbk], 1u);
      cmp[slot] = make_uint2((ot << 4) | (ky & 15u), __float_as_uint(wgt[e0 + i]));
      bktid[slot] = (unsigned char)bbk;
    }
    __syncthreads();
    for (int s = tid; s < len; s += 1024) {        // coalesced run copy-out
      unsigned bbk = bktid[s];
      out[myBase[bbk] + ((unsigned)s - baseL[bbk])] = cmp[s];
    }
    __syncthreads();
  }
}

// ---- K4/K5: per-bucket fine sort + select-free pipelined accumulation. --
// Wave wv owns node l=wv (both parts). Loads are unconditional with clamped
// index; only the WEIGHT is predicated (integer test, no memory dep).
__global__ void __launch_bounds__(1024) k_pass(
    const uint2* __restrict__ rec, const unsigned* __restrict__ seg,
    const float* __restrict__ vals, const float* __restrict__ x_t,
    const float* __restrict__ fx_t, float* __restrict__ eps_t,
    float* __restrict__ out, int N, int mode) {
  __shared__ uint2 srt[kTile];           // 20 KB node-sorted records
  __shared__ unsigned hW[16 * kNPB];     // per-wave private hist
  __shared__ unsigned wbase[16 * kNPB];  // absolute slot base per (wave,node)
  __shared__ unsigned wcur[16 * kNPB];
  __shared__ unsigned h[kNPB], hb[kNPB];
  __shared__ float red[1024];
  int tid = threadIdx.x, t = blockIdx.x;
  int segb = (int)seg[t], sege = (int)seg[t + 1];
  int wv = tid >> 6;
  int b = tid & 31, hw = tid >> 5, l = hw >> 1, part = hw & 1;
  float acc = 0.0f;

  for (int t0 = segb; t0 < sege; t0 += kTile) {    // 1 tile except 11-sigma tail
    int len = min(kTile, sege - t0);
    if (tid < 16 * kNPB) { hW[tid] = 0u; wcur[tid] = 0u; }
    __syncthreads();
    for (int i = tid; i < len; i += 1024)          // privatized 16-bin hist
      atomicAdd(&hW[wv * kNPB + (rec[t0 + i].x & 15u)], 1u);
    __syncthreads();
    if (tid < kNPB) {                              // cross-wave prefix per node
      unsigned run = 0;
#pragma unroll
      for (int w2 = 0; w2 < 16; ++w2) {
        unsigned c = hW[w2 * kNPB + tid];
        wbase[w2 * kNPB + tid] = run;
        run += c;
      }
      h[tid] = run;
    }
    __syncthreads();
    if (tid == 0) {                                // 16-elem excl scan
      unsigned run = 0;
#pragma unroll
      for (int l2 = 0; l2 < kNPB; ++l2) { hb[l2] = run; run += h[l2]; }
    }
    __syncthreads();
    if (tid < 16 * kNPB) wbase[tid] += hb[tid & (kNPB - 1)];
    __syncthreads();
    for (int i = tid; i < len; i += 1024) {        // fine sort (per-wave cursors)
      uint2 r = rec[t0 + i];
      unsigned lx = r.x & 15u;
      srt[wbase[wv * kNPB + lx] + atomicAdd(&wcur[wv * kNPB + lx], 1u)] = r;
    }
    __syncthreads();

    int beg = (int)hb[l] + part, end = (int)hb[l] + (int)h[l];
    int last = end - 1; if (last < 0) last = 0;
    uint2 r0, r1, r2, r3, r4, r5, r6, r7;
    float v0, v1, v2, v3, v4, v5, v6, v7;
#define PC_LOAD(d)                                                   \
    { int p = beg + 2 * (d); uint2 rr = srt[min(p, last)];           \
      r##d = rr; v##d = vals[(((rr.x >> 4) & 4095u) << kLogB) + b]; }
    PC_LOAD(0) PC_LOAD(1) PC_LOAD(2) PC_LOAD(3)
    PC_LOAD(4) PC_LOAD(5) PC_LOAD(6) PC_LOAD(7)
#undef PC_LOAD
    int i = beg;
    while (i < end) {
#define PC_STEP(d)                                                   \
      { float wt = (i + 2 * (d) < end) ? __uint_as_float(r##d.y) : 0.0f; \
        acc = fmaf(wt, v##d, acc);                                   \
        int p = i + 16 + 2 * (d); uint2 rr = srt[min(p, last)];      \
        r##d = rr; v##d = vals[(((rr.x >> 4) & 4095u) << kLogB) + b]; }
      PC_STEP(0) PC_STEP(1) PC_STEP(2) PC_STEP(3)
      PC_STEP(4) PC_STEP(5) PC_STEP(6) PC_STEP(7)
#undef PC_STEP
      i += 16;
    }
    __syncthreads();                               // srt/hW reused next tile
  }

  red[tid] = acc;
  __syncthreads();
  if (part == 0) {                                 // combine 2 parts, write
    float s = red[tid] + red[tid + 32];
    int n = t * kNPB + l;
    int j = (n << kLogB) + b;
    if (mode == 0) {
      out[b * N + n] = s;                          // mu: 16 nodes = full 64B line
      eps_t[j] = x_t[j] - s;
    } else {
      float fx = fx_t[j];
      out[b * N + n] = fmaf(1.0f - fx * fx, s, -eps_t[j]);  // dx
    }
  }
}

extern "C" void kernel_launch(void* const* d_in, const int* in_sizes, int n_in,
                              void* d_out, int out_size, void* d_ws, size_t ws_size,
                              hipStream_t stream) {
  const float* x    = (const float*)d_in[0];
  const float* w    = (const float*)d_in[1];
  const int*   esrc = (const int*)d_in[2];
  const int*   edst = (const int*)d_in[3];

  int BN = in_sizes[0];                  // 131072
  int E  = in_sizes[1];                  // 524288
  int N  = BN / kB;                      // 4096
  int nBB = (E + kChunk - 1) / kChunk;   // 256

  float* ws    = (float*)d_ws;
  float* x_t   = ws;                     // [BN]
  float* fx_t  = ws + (size_t)BN;        // [BN]
  float* eps_t = ws + 2 * (size_t)BN;    // [BN]
  unsigned* cntA = (unsigned*)(ws + 3 * (size_t)BN);    // [nBB*256] 256 KB
  unsigned* cntB = cntA + (size_t)nBB * kBkt;
  unsigned* baseA = cntB + (size_t)nBB * kBkt;          // [nBB*256]
  unsigned* baseB = baseA + (size_t)nBB * kBkt;
  unsigned* segA = baseB + (size_t)nBB * kBkt;          // [257] (512 pad)
  unsigned* segB = segA + 512;
  uint2* recA = (uint2*)(segB + 512);                   // [E] 4 MB dense
  uint2* recB = recA + (size_t)E;                       // [E] 4 MB dense

  float* out_mu = (float*)d_out;
  float* out_dx = (float*)d_out + BN;

  k_hist<<<nBB + (N >> 6), 1024, 0, stream>>>(esrc, edst, x, x_t, fx_t,
                                              cntA, cntB, N, E, nBB);
  k_scan<<<2, 1024, 0, stream>>>(cntA, cntB, baseA, baseB, segA, segB, nBB);
  k_scatter<<<nBB, 1024, 0, stream>>>(esrc, edst, w, cntA, cntB, baseA, baseB,
                                      recA, recB, E, nBB);
  // Pass 1: mu[n] = sum_{e: dst=n} w_e * fx[src_e]; eps = x - mu.
  k_pass<<<kBkt, 1024, 0, stream>>>(recA, segA, fx_t, x_t, fx_t,
                                    eps_t, out_mu, N, 0);
  // Pass 2: dx[n] = -eps[n] + f'(x_n) * sum_{e: src=n} w_e * eps[dst_e].
  k_pass<<<kBkt, 1024, 0, stream>>>(recB, segB, eps_t, x_t, fx_t,
                                    eps_t, out_dx, N, 1);
}